// Round 16
// baseline (2100.114 us; speedup 1.0000x reference)
//
#include <hip/hip_runtime.h>

#define NN 128000
#define EE 1024000
#define HH 128
#define GG 512
#define SMAX 1000
#define NCHUNK 500   // 500 * 256 = 128000

typedef unsigned int u32;
typedef unsigned short u16;

// ---------------- workspace layout (floats, then ints) ----------------
constexpr size_t NH     = (size_t)NN*HH;              // 16,384,000
constexpr size_t F_H    = 0;                          // h (persist, f32)
constexpr size_t F_A    = NH;                         // work A: xagg / gi overlay
constexpr size_t F_B    = 2*NH;                       // work B: qt / h2
constexpr size_t F_NODE = F_A + (size_t)NN*192;       // bf16 node_out overlay
constexpr size_t F_CN   = 3*NH;                       // 4*128 normalized centers
constexpr size_t F_WKT  = F_CN   + 512;               // 3*128*128 Wk^T
constexpr size_t F_WQK  = F_WKT  + 3*16384;           // 3*128*128 Wq@Wk^T
constexpr size_t F_BQK  = F_WQK  + 3*16384;           // 3*128  Wk@bq
constexpr size_t F_CW   = F_BQK  + 3*128;             // 128*384 projW@Wih^T
constexpr size_t F_PEW  = F_CW   + 128*384;           // 1000*384
constexpr size_t F_PEB  = F_PEW  + 1000*384;          // 1000*128
constexpr size_t F_END  = F_PEB  + 1000*128;

constexpr size_t I_ROWP = 0;                          // N+8 CSR row ptr
constexpr size_t I_CUR  = I_ROWP + NN + 8;
constexpr size_t I_COL  = I_CUR  + NN;                // E
constexpr size_t I_GRP  = I_COL  + EE;
constexpr size_t I_INV  = I_GRP  + NN;
constexpr size_t I_POS  = I_INV  + NN;
constexpr size_t I_GN   = I_POS  + NN;                // 512*1000
constexpr size_t I_CNT  = I_GN   + (size_t)GG*SMAX;
constexpr size_t I_CH   = I_CNT  + GG;                // 500*512
constexpr size_t I_BS   = I_CH   + (size_t)NCHUNK*GG;
constexpr size_t I_WT   = I_BS   + 512;               // 384*64 packed f16 Whh^T rows
constexpr size_t I_END  = I_WT   + 64*384;

constexpr size_t WS_NEEDED = F_END*4 + I_END*4;

__device__ inline float wredf(float v){
  #pragma unroll
  for (int o = 32; o; o >>= 1) v += __shfl_xor(v, o);
  return v;
}
__device__ inline u32 bf16rne(float f){
  u32 u = __float_as_uint(f);
  return (u + 0x7fffu + ((u >> 16) & 1u)) >> 16;
}
__device__ inline float bf2f(u16 u){
  return __uint_as_float(((u32)u) << 16);
}
__device__ inline float frcp(float x){
#if __has_builtin(__builtin_amdgcn_rcpf)
  return __builtin_amdgcn_rcpf(x);
#else
  return 1.f / x;
#endif
}

typedef _Float16 h2_t __attribute__((ext_vector_type(2)));
__device__ inline float dot2f(u32 w, u32 h, float acc){
#if __has_builtin(__builtin_amdgcn_fdot2)
  return __builtin_amdgcn_fdot2(__builtin_bit_cast(h2_t, w),
                                __builtin_bit_cast(h2_t, h), acc, false);
#else
  float r;
  asm("v_dot2_f32_f16 %0, %1, %2, %3" : "=v"(r) : "v"(w), "v"(h), "v"(acc));
  return r;
#endif
}
#define PIN4(v) asm volatile("" : "+v"((v).x), "+v"((v).y), "+v"((v).z), "+v"((v).w))

// ---------------- ws-size diagnostic sentinel ----------------
__global__ void k_sentinel(float* __restrict__ out, int n, float val){
  int i = blockIdx.x * 256 + threadIdx.x;
  if (i < n) out[i] = val;
}

// ---------------- CSR build ----------------
__global__ void k_zero(int* __restrict__ p){
  p[blockIdx.x * 256 + threadIdx.x] = 0;
}
__global__ void k_hist(const int* __restrict__ dst, int* __restrict__ deg){
  int e = blockIdx.x * 256 + threadIdx.x;
  atomicAdd(&deg[dst[e]], 1);
}
__global__ void k_s1(const int* __restrict__ deg, int* __restrict__ bsum){
  __shared__ int red[256];
  int t = threadIdx.x;
  red[t] = deg[blockIdx.x * 256 + t];
  __syncthreads();
  for (int s = 128; s; s >>= 1){ if (t < s) red[t] += red[t + s]; __syncthreads(); }
  if (!t) bsum[blockIdx.x] = red[0];
}
__global__ void k_s2(int* __restrict__ bsum){
  __shared__ int arr[512];
  int t = threadIdx.x;
  int v0 = (t < NCHUNK) ? bsum[t] : 0;
  arr[t] = v0; __syncthreads();
  for (int off = 1; off < 512; off <<= 1){
    int v = (t >= off) ? arr[t - off] : 0;
    __syncthreads();
    arr[t] += v;
    __syncthreads();
  }
  if (t < NCHUNK) bsum[t] = arr[t] - v0;   // exclusive
}
__global__ void k_s3(const int* __restrict__ bsum, int* __restrict__ row_ptr,
                     int* __restrict__ cursor){
  __shared__ int arr[256];
  int t = threadIdx.x;
  int i = blockIdx.x * 256 + t;
  int v0 = cursor[i];
  arr[t] = v0; __syncthreads();
  for (int off = 1; off < 256; off <<= 1){
    int v = (t >= off) ? arr[t - off] : 0;
    __syncthreads();
    arr[t] += v;
    __syncthreads();
  }
  int exc = arr[t] - v0 + bsum[blockIdx.x];
  row_ptr[i] = exc;
  cursor[i]  = exc;
  if (i == 0) row_ptr[NN] = EE;
}
__global__ void k_scatter(const int* __restrict__ src, const int* __restrict__ dst,
                          int* __restrict__ cursor, int* __restrict__ col){
  int e = blockIdx.x * 256 + threadIdx.x;
  int idx = atomicAdd(&cursor[dst[e]], 1);
  col[idx] = src[e];
}

// ---------------- centers: normalize + distance ----------------
__global__ void k_setup(const float* __restrict__ centers, float* __restrict__ cn,
                        float* __restrict__ dist_out){
  __shared__ float red[128];
  int t = threadIdx.x;
  for (int l = 0; l < 4; ++l){
    float v = centers[l*128 + t];
    red[t] = v * v; __syncthreads();
    for (int s = 64; s; s >>= 1){ if (t < s) red[t] += red[t + s]; __syncthreads(); }
    float nrm = sqrtf(red[0]);
    __syncthreads();
    cn[l*128 + t] = v / fmaxf(nrm, 1e-8f);
  }
  const int iu0[6] = {0,0,0,1,1,2}, iu1[6] = {1,2,3,2,3,3};
  __shared__ float dv[6];
  for (int p = 0; p < 6; ++p){
    float d = centers[iu0[p]*128 + t] - centers[iu1[p]*128 + t];
    red[t] = d * d; __syncthreads();
    for (int s = 64; s; s >>= 1){ if (t < s) red[t] += red[t + s]; __syncthreads(); }
    if (!t) dv[p] = sqrtf(red[0]);
    __syncthreads();
  }
  if (!t){
    float mean = 0.f;
    for (int p = 0; p < 6; ++p) mean += dv[p];
    mean /= 6.f;
    float var = 0.f;
    for (int p = 0; p < 6; ++p){ float d = dv[p] - mean; var += d * d; }
    var /= 5.f;                              // ddof=1
    dist_out[0] = -var;
  }
}

// ---------------- pos-enc tables + weight transforms ----------------
__global__ void k_pe(const float* __restrict__ projb, float* __restrict__ peb){
  int p = blockIdx.x, t = threadIdx.x;     // 1000 x 128
  float ex  = (float)(t >> 1) * (-2.0f * 9.210340371976184f / 128.0f);
  float ang = (float)p * expf(ex);
  float v = (t & 1) ? cosf(ang) : sinf(ang);
  peb[p*128 + t] = v + projb[t];
}
__global__ void k_pew(const float* __restrict__ peb, const float* __restrict__ Wih,
                      const float* __restrict__ bih, float* __restrict__ pew){
  int p = blockIdx.x;                       // 1000
  int j = blockIdx.y * 128 + threadIdx.x;   // 384
  const float* pb = peb + p*128;
  const float* wr = Wih + (size_t)j*128;
  float acc = bih[j];
  #pragma unroll 4
  for (int m = 0; m < 128; ++m) acc += pb[m] * wr[m];
  pew[(size_t)p*384 + j] = acc;
}
__global__ void k_combw(const float* __restrict__ projW, const float* __restrict__ Wih,
                        float* __restrict__ cw){
  int kk = blockIdx.x;                      // 128
  int j  = blockIdx.y * 128 + threadIdx.x;  // 384
  const float* pr = projW + (size_t)kk*128;
  const float* wr = Wih + (size_t)j*128;
  float acc = 0.f;
  #pragma unroll 4
  for (int m = 0; m < 128; ++m) acc += pr[m] * wr[m];
  cw[(size_t)kk*384 + j] = acc;
}
// Wk^T per layer
__global__ void k_tr(const float* __restrict__ Wk, float* __restrict__ wkt){
  int kk = blockIdx.x, l = blockIdx.y, c = threadIdx.x;
  wkt[(size_t)l*16384 + kk*128 + c] = Wk[(size_t)l*16384 + c*128 + kk];
}
// out[l][i] = row_i(M_l) . v_l
__global__ void k_mv(const float* __restrict__ M, const float* __restrict__ v,
                     float* __restrict__ out){
  int l = blockIdx.x, i = threadIdx.x;
  const float* row = M + (size_t)l*16384 + (size_t)i*128;
  const float* vv = v + l*128;
  float acc = 0.f;
  #pragma unroll 4
  for (int j = 0; j < 128; ++j) acc += row[j] * vv[j];
  out[l*128 + i] = acc;
}
// pack Whh rows as f16x2 along k
__global__ void k_packwhh16(const float* __restrict__ Whh, u32* __restrict__ wt){
  int kp = blockIdx.x;                      // 64
  int j  = blockIdx.y * 128 + threadIdx.x;  // 384
  _Float16 a = (_Float16)Whh[(size_t)j*128 + 2*kp];
  _Float16 b = (_Float16)Whh[(size_t)j*128 + 2*kp + 1];
  u32 lo = (u32)__builtin_bit_cast(u16, a);
  u32 hi = (u32)__builtin_bit_cast(u16, b);
  wt[(size_t)j*64 + kp] = (hi << 16) | lo;
}

// ---------------- GEMM v5: 128x128 tile, 8x8 acc; optional K=256; optional LN ----
__global__ __launch_bounds__(256, 2) void k_gemm(
    const float* __restrict__ X, const float* __restrict__ W, int ldw,
    const float* __restrict__ X2, const float* __restrict__ W2,
    const float* __restrict__ bias, const float* __restrict__ pew,
    const int* __restrict__ pos, float* __restrict__ out,
    u16* __restrict__ outb, int ldo,
    const float* __restrict__ lng, const float* __restrict__ lnb,
    const float* __restrict__ bvv, const int* __restrict__ rowp){
  __shared__ __align__(16) float Wl[64*132];
  __shared__ __align__(16) float Xl[64*132];
  int tid = threadIdx.x;
  int rb = blockIdx.x * 128;
  int cb = blockIdx.y * 128;
  int rg = tid >> 4;
  int cg = tid & 15;
  int kxor = (cg >> 2) & 3;
  float acc[8][8];
  #pragma unroll
  for (int a = 0; a < 8; ++a)
    #pragma unroll
    for (int b = 0; b < 8; ++b) acc[a][b] = 0.f;
  int nhalf = X2 ? 4 : 2;
  for (int half = 0; half < nhalf; ++half){
    const float* Xs = (half < 2) ? X : X2;
    const float* Ws = (half < 2) ? W : W2;
    int ldws = (half < 2) ? ldw : 128;
    int hk = half & 1;
    __syncthreads();
    #pragma unroll
    for (int it = 0; it < 8; ++it){
      int idx = it*256 + tid;
      int kk = idx >> 5, c4 = idx & 31;
      *(float4*)&Wl[kk*132 + c4*4] =
          *(const float4*)&Ws[(size_t)(hk*64 + kk)*ldws + cb + c4*4];
    }
    #pragma unroll
    for (int it = 0; it < 8; ++it){
      int idx = it*256 + tid;
      int r = idx >> 4, c4 = idx & 15;
      float4 xv = *(const float4*)&Xs[(size_t)(rb + r)*128 + hk*64 + c4*4];
      Xl[(c4*4+0)*132 + r] = xv.x;
      Xl[(c4*4+1)*132 + r] = xv.y;
      Xl[(c4*4+2)*132 + r] = xv.z;
      Xl[(c4*4+3)*132 + r] = xv.w;
    }
    __syncthreads();
    #pragma unroll 2
    for (int kk = 0; kk < 64; ++kk){
      int kx = kk ^ kxor;
      float4 wa = *(const float4*)&Wl[kx*132 + cg*8];
      float4 wb = *(const float4*)&Wl[kx*132 + cg*8 + 4];
      float4 xa = *(const float4*)&Xl[kx*132 + rg*8];
      float4 xb = *(const float4*)&Xl[kx*132 + rg*8 + 4];
      float xs[8] = {xa.x, xa.y, xa.z, xa.w, xb.x, xb.y, xb.z, xb.w};
      float ws[8] = {wa.x, wa.y, wa.z, wa.w, wb.x, wb.y, wb.z, wb.w};
      #pragma unroll
      for (int rr = 0; rr < 8; ++rr)
        #pragma unroll
        for (int j = 0; j < 8; ++j) acc[rr][j] += xs[rr] * ws[j];
    }
  }
  if (lng){
    float gv[8], bl[8], bb[8], vv[8];
    #pragma unroll
    for (int j = 0; j < 8; ++j){
      int c = cg*8 + j;
      gv[j] = lng[c]; bl[j] = lnb[c]; bb[j] = bias[c]; vv[j] = bvv[c];
    }
    #pragma unroll
    for (int rr = 0; rr < 8; ++rr){
      int r = rb + rg*8 + rr;
      bool deg = rowp[r+1] > rowp[r];
      float rs = 0.f, rq = 0.f;
      #pragma unroll
      for (int j = 0; j < 8; ++j){
        float v = acc[rr][j] + bb[j] + (deg ? vv[j] : 0.f);
        acc[rr][j] = v;
        rs += v; rq += v*v;
      }
      #pragma unroll
      for (int o = 8; o; o >>= 1){ rs += __shfl_xor(rs, o); rq += __shfl_xor(rq, o); }
      float mu = rs * 0.0078125f;
      float var = rq * 0.0078125f - mu*mu;
      float rstd = rsqrtf(var + 1e-5f);
      float ov[8];
      #pragma unroll
      for (int j = 0; j < 8; ++j)
        ov[j] = fmaxf((acc[rr][j] - mu)*rstd*gv[j] + bl[j], 0.f);
      float* op = out + (size_t)r*128 + cg*8;
      *(float4*)op       = *(const float4*)&ov[0];
      *(float4*)(op + 4) = *(const float4*)&ov[4];
    }
    return;
  }
  #pragma unroll
  for (int rr = 0; rr < 8; ++rr){
    int r = rb + rg*8 + rr;
    float bv[8];
    if (pos){
      const float* pw = pew + (size_t)pos[r]*384 + cb + cg*8;
      #pragma unroll
      for (int j = 0; j < 8; ++j) bv[j] = pw[j];
    } else if (bias){
      #pragma unroll
      for (int j = 0; j < 8; ++j) bv[j] = bias[cb + cg*8 + j];
    } else {
      #pragma unroll
      for (int j = 0; j < 8; ++j) bv[j] = 0.f;
    }
    if (outb){
      u16 ob[8];
      #pragma unroll
      for (int j = 0; j < 8; ++j) ob[j] = (u16)bf16rne(acc[rr][j] + bv[j]);
      *(uint4*)(outb + (size_t)r*ldo + cb + cg*8) = *(const uint4*)ob;
    } else {
      float ov[8];
      #pragma unroll
      for (int j = 0; j < 8; ++j) ov[j] = acc[rr][j] + bv[j];
      float* op = out + (size_t)r*ldo + cb + cg*8;
      *(float4*)op       = *(const float4*)&ov[0];
      *(float4*)(op + 4) = *(const float4*)&ov[4];
    }
  }
}

// ---------------- fused edge v4: no qb, pair-unrolled ----------------
__global__ __launch_bounds__(256) void k_edge(
    const float* __restrict__ qt, const float* __restrict__ xsrc,
    const int* __restrict__ row_ptr, const int* __restrict__ col,
    float* __restrict__ xagg){
  int d = blockIdx.x * 8 + (threadIdx.x >> 5);
  int lane = threadIdx.x & 31;
  int e0 = row_ptr[d], e1 = row_ptr[d+1];
  if (e0 == e1){
    *(float4*)&xagg[(size_t)d*128 + lane*4] = make_float4(0.f, 0.f, 0.f, 0.f);
    return;
  }
  const float S = 0.08838834764831845f;   // 1/sqrt(128)
  float4 qv = *(const float4*)&qt[(size_t)d*128 + lane*4];
  float ss0 = 0.f, ss1 = 0.f;
  float4 A0 = make_float4(0.f,0.f,0.f,0.f), A1 = make_float4(0.f,0.f,0.f,0.f);
  int e = e0;
  for (; e + 1 < e1; e += 2){
    float4 x0 = *(const float4*)&xsrc[(size_t)col[e]  *128 + lane*4];
    float4 x1 = *(const float4*)&xsrc[(size_t)col[e+1]*128 + lane*4];
    float p0 = qv.x*x0.x + qv.y*x0.y + qv.z*x0.z + qv.w*x0.w;
    float p1 = qv.x*x1.x + qv.y*x1.y + qv.z*x1.z + qv.w*x1.w;
    #pragma unroll
    for (int o = 16; o; o >>= 1){ p0 += __shfl_xor(p0, o); p1 += __shfl_xor(p1, o); }
    float el0 = __expf(p0 * S);
    float el1 = __expf(p1 * S);
    ss0 += el0; ss1 += el1;
    A0.x += el0*x0.x; A0.y += el0*x0.y; A0.z += el0*x0.z; A0.w += el0*x0.w;
    A1.x += el1*x1.x; A1.y += el1*x1.y; A1.z += el1*x1.z; A1.w += el1*x1.w;
  }
  if (e < e1){
    float4 x0 = *(const float4*)&xsrc[(size_t)col[e]*128 + lane*4];
    float p0 = qv.x*x0.x + qv.y*x0.y + qv.z*x0.z + qv.w*x0.w;
    #pragma unroll
    for (int o = 16; o; o >>= 1) p0 += __shfl_xor(p0, o);
    float el0 = __expf(p0 * S);
    ss0 += el0;
    A0.x += el0*x0.x; A0.y += el0*x0.y; A0.z += el0*x0.z; A0.w += el0*x0.w;
  }
  float inv = 1.f / (ss0 + ss1);
  *(float4*)&xagg[(size_t)d*128 + lane*4] =
      make_float4((A0.x+A1.x)*inv, (A0.y+A1.y)*inv, (A0.z+A1.z)*inv, (A0.w+A1.w)*inv);
}

// ---------------- conv-3 lnrelu fused with cluster assignment ----------------
__global__ __launch_bounds__(256) void k_lnrelu_cls(
    const float* __restrict__ in, const float* __restrict__ g,
    const float* __restrict__ b, const float* __restrict__ bvv,
    const int* __restrict__ rowp, float* __restrict__ outp,
    const float* __restrict__ cn, const int* __restrict__ batch,
    const int* __restrict__ callsq, int* __restrict__ grp, int* __restrict__ inv){
  int node = blockIdx.x * 4 + (threadIdx.x >> 6);
  int lane = threadIdx.x & 63;
  float x0 = in[(size_t)node*128 + 2*lane], x1 = in[(size_t)node*128 + 2*lane + 1];
  if (rowp[node+1] > rowp[node]){
    x0 += bvv[2*lane];
    x1 += bvv[2*lane + 1];
  }
  float s = wredf(x0 + x1);
  float qq = wredf(x0*x0 + x1*x1);
  float mu = s * 0.0078125f;
  float var = qq * 0.0078125f - mu*mu;
  float rstd = rsqrtf(var + 1e-5f);
  float y0 = fmaxf((x0 - mu)*rstd*g[2*lane]   + b[2*lane],   0.f);
  float y1 = fmaxf((x1 - mu)*rstd*g[2*lane+1] + b[2*lane+1], 0.f);
  outp[(size_t)node*128 + 2*lane]     = y0;
  outp[(size_t)node*128 + 2*lane + 1] = y1;
  float p0 = y0*cn[      2*lane] + y1*cn[      2*lane+1];
  float p1 = y0*cn[128 + 2*lane] + y1*cn[128 + 2*lane+1];
  float p2 = y0*cn[256 + 2*lane] + y1*cn[256 + 2*lane+1];
  float p3 = y0*cn[384 + 2*lane] + y1*cn[384 + 2*lane+1];
  p0 = wredf(p0); p1 = wredf(p1); p2 = wredf(p2); p3 = wredf(p3);
  if (lane == 0){
    float best = p0; int bi = 0;
    if (p1 > best){ best = p1; bi = 1; }
    if (p2 > best){ best = p2; bi = 2; }
    if (p3 > best){ best = p3; bi = 3; }
    grp[node] = batch[node]*4 + bi;
    inv[callsq[node]] = node;
  }
}

// ---------------- grouping: chunked multisplit ----------------
__global__ __launch_bounds__(256) void k_g1(const int* __restrict__ inv,
                                            const int* __restrict__ grp,
                                            int* __restrict__ ch){
  __shared__ int hist[GG];
  int c = blockIdx.x, t = threadIdx.x;
  hist[t] = 0; hist[t + 256] = 0;
  __syncthreads();
  int g = grp[inv[c*256 + t]];
  atomicAdd(&hist[g], 1);
  __syncthreads();
  ch[c*GG + t] = hist[t];
  ch[c*GG + 256 + t] = hist[256 + t];
}
__global__ void k_g2(int* __restrict__ ch, int* __restrict__ cnt){
  __shared__ int arr[512];
  int g = blockIdx.x, t = threadIdx.x;
  int v0 = (t < NCHUNK) ? ch[(size_t)t*GG + g] : 0;
  arr[t] = v0; __syncthreads();
  for (int off = 1; off < 512; off <<= 1){
    int v = (t >= off) ? arr[t - off] : 0;
    __syncthreads();
    arr[t] += v;
    __syncthreads();
  }
  if (t < NCHUNK) ch[(size_t)t*GG + g] = arr[t] - v0;
  if (t == 511) cnt[g] = arr[511];
}
__global__ __launch_bounds__(256) void k_g3(
    const int* __restrict__ inv, const int* __restrict__ grp,
    const int* __restrict__ ch, int* __restrict__ pos, int* __restrict__ gn){
  __shared__ int hist[GG];
  int c = blockIdx.x, t = threadIdx.x;
  hist[t] = 0; hist[t + 256] = 0;
  __syncthreads();
  int node = inv[c*256 + t];
  int g = grp[node];
  int lane = t & 63, w = t >> 6;
  int before = 0, total = 0;
  for (int j = 0; j < 64; ++j){
    int gj = __shfl(g, j);
    if (gj == g){ total++; if (j < lane) before++; }
  }
  int base = 0;
  for (int wv = 0; wv < 4; ++wv){
    if (w == wv){
      base = hist[g];
      if (before == total - 1) hist[g] = base + total;
    }
    __syncthreads();
  }
  int p = ch[c*GG + g] + base + before;
  pos[node] = p;
  gn[(size_t)g*SMAX + p] = node;
}

// ---------------- GRU v11: 2 waves/group, full-k per thread, no pair-reduce -------
// 128 threads, thread j owns output j with the full k=128 dot (48 pinned uint4
// weight regs at waves_per_eu(1,1) -> 512-reg budget). Barrier is 2-wave (was
// 4-wave); LDS h reads are pure broadcast. Dot chains split even/odd-s.
__global__ __launch_bounds__(128)
__attribute__((amdgpu_waves_per_eu(1, 1)))
void k_gru(
    const u16* __restrict__ gi, const u32* __restrict__ wt,
    const float* __restrict__ bhh, const int* __restrict__ gn,
    const int* __restrict__ cnt, u16* __restrict__ node_out){
  __shared__ __align__(16) u16 hb16[2][128];
  int j = threadIdx.x;         // output index 0..127
  int g = blockIdx.x;
  int my = cnt[g];
  if (my <= 1) return;
  // ---- full-k weight rows into registers (once), pinned ----
  uint4 wr_[16], wz_[16], wn_[16];
  {
    const uint4* wt4 = (const uint4*)wt;
    size_t b0 = (size_t)(0*128 + j)*16;
    size_t b1 = (size_t)(1*128 + j)*16;
    size_t b2 = (size_t)(2*128 + j)*16;
    #pragma unroll
    for (int s = 0; s < 16; ++s){
      wr_[s] = wt4[b0 + s];
      wz_[s] = wt4[b1 + s];
      wn_[s] = wt4[b2 + s];
    }
    #pragma unroll
    for (int s = 0; s < 16; ++s){
      PIN4(wr_[s]); PIN4(wz_[s]); PIN4(wn_[s]);
    }
  }
  hb16[0][j] = 0;
  float br = bhh[j], bz = bhh[128 + j], bn = bhh[256 + j];
  const int* gnr = gn + (size_t)g*SMAX;
  float hprev = 0.f;
  int node = gnr[0];
  // raw u16 lookahead: loads issued one step before their convert
  const u16* g0 = gi + (size_t)node*384;
  u16 rxr = g0[j], rxz = g0[128 + j], rxn = g0[256 + j];
  __syncthreads();                       // init (full drain once)
  for (int p = 0; p < my; ++p){
    int cur = p & 1, nxt = cur ^ 1;
    int nodeN = gnr[min(p + 1, my - 1)];
    float xr = bf2f(rxr), xz = bf2f(rxz), xn = bf2f(rxn);
    const u16* gN = gi + (size_t)nodeN*384;
    rxr = gN[j]; rxz = gN[128 + j]; rxn = gN[256 + j];
    // broadcast h read: all lanes read the same 16 uint4
    const uint4* HB = (const uint4*)&hb16[cur][0];
    uint4 hh[16];
    #pragma unroll
    for (int s = 0; s < 16; ++s) hh[s] = HB[s];
    __builtin_amdgcn_s_setprio(1);
    float ar0 = 0.f, ar1 = 0.f, az0 = 0.f, az1 = 0.f, an0 = 0.f, an1 = 0.f;
    #pragma unroll
    for (int s = 0; s < 16; s += 2){
      uint4 h0 = hh[s], h1 = hh[s + 1];
      uint4 r0 = wr_[s], r1 = wr_[s + 1];
      uint4 z0 = wz_[s], z1 = wz_[s + 1];
      uint4 n0 = wn_[s], n1 = wn_[s + 1];
      ar0 = dot2f(r0.x, h0.x, ar0); ar1 = dot2f(r1.x, h1.x, ar1);
      az0 = dot2f(z0.x, h0.x, az0); az1 = dot2f(z1.x, h1.x, az1);
      an0 = dot2f(n0.x, h0.x, an0); an1 = dot2f(n1.x, h1.x, an1);
      ar0 = dot2f(r0.y, h0.y, ar0); ar1 = dot2f(r1.y, h1.y, ar1);
      az0 = dot2f(z0.y, h0.y, az0); az1 = dot2f(z1.y, h1.y, az1);
      an0 = dot2f(n0.y, h0.y, an0); an1 = dot2f(n1.y, h1.y, an1);
      ar0 = dot2f(r0.z, h0.z, ar0); ar1 = dot2f(r1.z, h1.z, ar1);
      az0 = dot2f(z0.z, h0.z, az0); az1 = dot2f(z1.z, h1.z, az1);
      an0 = dot2f(n0.z, h0.z, an0); an1 = dot2f(n1.z, h1.z, an1);
      ar0 = dot2f(r0.w, h0.w, ar0); ar1 = dot2f(r1.w, h1.w, ar1);
      az0 = dot2f(z0.w, h0.w, az0); az1 = dot2f(z1.w, h1.w, az1);
      an0 = dot2f(n0.w, h0.w, an0); an1 = dot2f(n1.w, h1.w, an1);
    }
    float ar = ar0 + ar1 + br;
    float az = az0 + az1 + bz;
    float an = an0 + an1 + bn;
    float er = __expf(-(xr + ar));
    float r  = frcp(1.f + er);
    float ez = __expf(-(xz + az));
    float z  = frcp(1.f + ez);
    float y  = xn + r * an;
    float e2 = __expf(-2.f * y);
    float n  = (1.f - e2) * frcp(1.f + e2);   // tanh(y)
    float hnew = n + z * (hprev - n);
    __builtin_amdgcn_s_setprio(0);
    hprev = hnew;
    _Float16 hf = (_Float16)hnew;
    hb16[nxt][j] = __builtin_bit_cast(u16, hf);
    // paired bf16 store: even j writes u32 {h[j], h[j+1]}
    u16 hbf = (u16)bf16rne(hnew);
    u32 pk = ((u32)(u16)__shfl_xor((int)hbf, 1) << 16) | (u32)hbf;
    if (!(j & 1))
      *(u32*)(node_out + (size_t)node*128 + j) = pk;
    node = nodeN;
    // lgkm-only 2-wave barrier: gi prefetch stays in flight
    asm volatile("s_waitcnt lgkmcnt(0)" ::: "memory");
    __builtin_amdgcn_s_barrier();
    asm volatile("" ::: "memory");
  }
}

// ---------------- head fused with post-GRU LN+ReLU ----------------
__global__ __launch_bounds__(256) void k_head(
    const float* __restrict__ h, const u16* __restrict__ node_out,
    const int* __restrict__ grp, const int* __restrict__ cnt,
    const float* __restrict__ sqg, const float* __restrict__ sqb,
    const float* __restrict__ l1W, const float* __restrict__ l1b,
    const float* __restrict__ l2W, const float* __restrict__ l2b,
    float* __restrict__ out){
  int node = blockIdx.x * 4 + (threadIdx.x >> 6);
  int lane = threadIdx.x & 63;
  bool single = (cnt[grp[node]] == 1);   // wave-uniform
  float x0, x1;
  if (single){
    x0 = h[(size_t)node*128 + 2*lane];
    x1 = h[(size_t)node*128 + 2*lane + 1];
  } else {
    float r0 = bf2f(node_out[(size_t)node*128 + 2*lane]);
    float r1 = bf2f(node_out[(size_t)node*128 + 2*lane + 1]);
    float s = wredf(r0 + r1);
    float qq = wredf(r0*r0 + r1*r1);
    float mu = s * 0.0078125f;
    float var = qq * 0.0078125f - mu*mu;
    float rstd = rsqrtf(var + 1e-5f);
    x0 = fmaxf((r0 - mu)*rstd*sqg[2*lane]   + sqb[2*lane],   0.f);
    x1 = fmaxf((r1 - mu)*rstd*sqg[2*lane+1] + sqb[2*lane+1], 0.f);
  }
  float acc[8];
  #pragma unroll
  for (int j = 0; j < 8; ++j)
    acc[j] = x0 * l1W[(2*lane)*8 + j] + x1 * l1W[(2*lane + 1)*8 + j];
  #pragma unroll
  for (int o = 32; o; o >>= 1)
    #pragma unroll
    for (int j = 0; j < 8; ++j) acc[j] += __shfl_xor(acc[j], o);
  if (lane == 0){
    float zz = l2b[0];
    #pragma unroll
    for (int j = 0; j < 8; ++j){
      float xx = acc[j] + l1b[j];
      float ge = 0.5f * xx * (1.f + erff(xx * 0.7071067811865476f));
      zz += ge * l2W[j];
    }
    out[node] = 1.f / (1.f + expf(-zz));
  }
}

extern "C" void kernel_launch(void* const* d_in, const int* in_sizes, int n_in,
                              void* d_out, int out_size, void* d_ws, size_t ws_size,
                              hipStream_t stream){
  float* out = (float*)d_out;

  // ---- ws-size guard ----
  if (ws_size < WS_NEEDED){
    float code = -(float)(ws_size >> 20);
    k_sentinel<<<(out_size + 255)/256, 256, 0, stream>>>(out, out_size, code);
    return;
  }

  const float* x       = (const float*)d_in[0];
  const int*   tei     = (const int*)d_in[1];
  const int*   callsq  = (const int*)d_in[2];
  const int*   batch   = (const int*)d_in[3];
  const float* Wq      = (const float*)d_in[4];
  const float* bq      = (const float*)d_in[5];
  const float* Wk      = (const float*)d_in[6];
  const float* bk      = (const float*)d_in[7];
  const float* Wv      = (const float*)d_in[8];
  const float* bv      = (const float*)d_in[9];
  const float* Wsk     = (const float*)d_in[10];
  const float* bsk     = (const float*)d_in[11];
  const float* lng     = (const float*)d_in[12];
  const float* lnb     = (const float*)d_in[13];
  const float* centers = (const float*)d_in[14];
  const float* projW   = (const float*)d_in[15];
  const float* projb   = (const float*)d_in[16];
  const float* Wih     = (const float*)d_in[17];
  const float* Whh     = (const float*)d_in[18];
  const float* bih     = (const float*)d_in[19];
  const float* bhh     = (const float*)d_in[20];
  const float* sqg     = (const float*)d_in[21];
  const float* sqb     = (const float*)d_in[22];
  const float* l1W     = (const float*)d_in[23];
  const float* l1b     = (const float*)d_in[24];
  const float* l2W     = (const float*)d_in[25];
  const float* l2b     = (const float*)d_in[26];

  float* wf = (float*)d_ws;
  float* f_h    = wf + F_H;
  float* f_a    = wf + F_A;
  float* f_b    = wf + F_B;
  float* f_cn   = wf + F_CN;
  float* f_wkt  = wf + F_WKT;
  float* f_wqk  = wf + F_WQK;
  float* f_bqk  = wf + F_BQK;
  float* f_cw   = wf + F_CW;
  float* f_pew  = wf + F_PEW;
  float* f_peb  = wf + F_PEB;
  u16*   gi_bf  = (u16*)(wf + F_A);
  u16*   no_bf  = (u16*)(wf + F_NODE);
  int* wi = (int*)(wf + F_END);
  int* i_rowp = wi + I_ROWP;
  int* i_cur  = wi + I_CUR;
  int* i_col  = wi + I_COL;
  int* i_grp  = wi + I_GRP;
  int* i_inv  = wi + I_INV;
  int* i_pos  = wi + I_POS;
  int* i_gn   = wi + I_GN;
  int* i_cnt  = wi + I_CNT;
  int* i_ch   = wi + I_CH;
  int* i_bs   = wi + I_BS;
  u32* i_wt   = (u32*)(wi + I_WT);

  const int* esrc = tei;
  const int* edst = tei + EE;

  // CSR build
  k_zero<<<NN/256, 256, 0, stream>>>(i_cur);
  k_hist<<<EE/256, 256, 0, stream>>>(edst, i_cur);
  k_s1<<<NCHUNK, 256, 0, stream>>>(i_cur, i_bs);
  k_s2<<<1, 512, 0, stream>>>(i_bs);
  k_s3<<<NCHUNK, 256, 0, stream>>>(i_bs, i_rowp, i_cur);
  k_scatter<<<EE/256, 256, 0, stream>>>(esrc, edst, i_cur, i_col);

  // centers, PE tables, folded conv weights, packed f16 Whh rows
  k_setup<<<1, 128, 0, stream>>>(centers, f_cn, out + NN);
  k_pe<<<1000, 128, 0, stream>>>(projb, f_peb);
  k_pew<<<dim3(1000, 3), 128, 0, stream>>>(f_peb, Wih, bih, f_pew);
  k_tr<<<dim3(128, 3), 128, 0, stream>>>(Wk, f_wkt);
  for (int i = 0; i < 3; ++i)
    k_gemm<<<dim3(1, 1), 256, 0, stream>>>(Wq + (size_t)i*16384, f_wkt + (size_t)i*16384,
        128, nullptr, nullptr, nullptr, nullptr, nullptr, f_wqk + (size_t)i*16384,
        nullptr, 128, nullptr, nullptr, nullptr, nullptr);   // Wqk = Wq@Wk^T
  k_mv<<<3, 128, 0, stream>>>(Wk, bq, f_bqk);                // bqk = Wk@bq
  k_combw<<<dim3(128, 3), 128, 0, stream>>>(projW, Wih, f_cw);
  k_packwhh16<<<dim3(64, 3), 128, 0, stream>>>(Whh, i_wt);

  // 3x TransformerConv + relu(LN)
  for (int i = 0; i < 3; ++i){
    const float* xin = i ? f_h : x;
    size_t wo = (size_t)i * 128 * 128, bo = (size_t)i * 128;
    // qt = xin@Wqk + bqk -> B
    k_gemm<<<dim3(NN/128, 1), 256, 0, stream>>>(xin, f_wqk + (size_t)i*16384, 128,
        nullptr, nullptr, f_bqk + bo, nullptr, nullptr, f_b, nullptr, 128,
        nullptr, nullptr, nullptr, nullptr);
    // fused edge: xagg -> A
    k_edge<<<NN/8, 256, 0, stream>>>(f_b, xin, i_rowp, i_col, f_a);
    // h2 = xagg@Wv + xin@Wsk + bsk; convs 1-2 fuse LN+ReLU into epilogue -> f_h
    if (i < 2){
      k_gemm<<<dim3(NN/128, 1), 256, 0, stream>>>(f_a, Wv + wo, 128, xin, Wsk + wo,
          bsk + bo, nullptr, nullptr, f_h, nullptr, 128,
          lng + bo, lnb + bo, bv + bo, i_rowp);
    } else {
      k_gemm<<<dim3(NN/128, 1), 256, 0, stream>>>(f_a, Wv + wo, 128, xin, Wsk + wo,
          bsk + bo, nullptr, nullptr, f_b, nullptr, 128,
          nullptr, nullptr, nullptr, nullptr);
      k_lnrelu_cls<<<NN/4, 256, 0, stream>>>(f_b, lng + bo, lnb + bo, bv + bo, i_rowp,
          f_h, f_cn, batch, callsq, i_grp, i_inv);
    }
  }

  // grouping
  k_g1<<<NCHUNK, 256, 0, stream>>>(i_inv, i_grp, i_ch);
  k_g2<<<GG, 512, 0, stream>>>(i_ch, i_cnt);
  k_g3<<<NCHUNK, 256, 0, stream>>>(i_inv, i_grp, i_ch, i_pos, i_gn);

  // gi = h @ (projW@Wih^T) + PEW[pos] -> bf16 overlay
  k_gemm<<<dim3(NN/128, 3), 256, 0, stream>>>(f_h, f_cw, 384, nullptr, nullptr,
      nullptr, f_pew, i_pos, nullptr, gi_bf, 384, nullptr, nullptr, nullptr, nullptr);

  // GRU (raw h out); LN+ReLU deferred into head; 128 threads = 2 waves per group
  k_gru<<<GG, 128, 0, stream>>>(gi_bf, i_wt, bhh, i_gn, i_cnt, no_bf);

  // head (fused post-LN)
  k_head<<<NN/4, 256, 0, stream>>>(f_h, no_bf, i_grp, i_cnt, sqg, sqb,
                                   l1W, l1b, l2W, l2b, out);
}

// Round 17
// 2063.034 us; speedup vs baseline: 1.0180x; 1.0180x over previous
//
#include <hip/hip_runtime.h>

#define NN 128000
#define EE 1024000
#define HH 128
#define GG 512
#define SMAX 1000
#define NCHUNK 500   // 500 * 256 = 128000

typedef unsigned int u32;
typedef unsigned short u16;

// ---------------- workspace layout (floats, then ints) ----------------
constexpr size_t NH     = (size_t)NN*HH;              // 16,384,000
constexpr size_t F_H    = 0;                          // h (persist, f32)
constexpr size_t F_A    = NH;                         // work A: xagg / gi overlay
constexpr size_t F_B    = 2*NH;                       // work B: qt / h2
constexpr size_t F_NODE = F_A + (size_t)NN*192;       // bf16 node_out overlay
constexpr size_t F_CN   = 3*NH;                       // 4*128 normalized centers
constexpr size_t F_WKT  = F_CN   + 512;               // 3*128*128 Wk^T
constexpr size_t F_WQK  = F_WKT  + 3*16384;           // 3*128*128 Wq@Wk^T
constexpr size_t F_BQK  = F_WQK  + 3*16384;           // 3*128  Wk@bq
constexpr size_t F_CW   = F_BQK  + 3*128;             // 128*384 projW@Wih^T
constexpr size_t F_PEW  = F_CW   + 128*384;           // 1000*384
constexpr size_t F_PEB  = F_PEW  + 1000*384;          // 1000*128
constexpr size_t F_END  = F_PEB  + 1000*128;

constexpr size_t I_ROWP = 0;                          // N+8 CSR row ptr
constexpr size_t I_CUR  = I_ROWP + NN + 8;
constexpr size_t I_COL  = I_CUR  + NN;                // E
constexpr size_t I_GRP  = I_COL  + EE;
constexpr size_t I_INV  = I_GRP  + NN;
constexpr size_t I_POS  = I_INV  + NN;
constexpr size_t I_GN   = I_POS  + NN;                // 512*1000
constexpr size_t I_CNT  = I_GN   + (size_t)GG*SMAX;
constexpr size_t I_CH   = I_CNT  + GG;                // 500*512
constexpr size_t I_BS   = I_CH   + (size_t)NCHUNK*GG;
constexpr size_t I_WT   = I_BS   + 512;               // 384*64 packed f16 Whh^T rows
constexpr size_t I_DST  = I_WT   + 64*384;            // N: packed dst row per node
constexpr size_t I_STARTS = I_DST + NN;               // 512 group starts
constexpr size_t I_END  = I_STARTS + 512;

constexpr size_t WS_NEEDED = F_END*4 + I_END*4;

__device__ inline float wredf(float v){
  #pragma unroll
  for (int o = 32; o; o >>= 1) v += __shfl_xor(v, o);
  return v;
}
__device__ inline u32 bf16rne(float f){
  u32 u = __float_as_uint(f);
  return (u + 0x7fffu + ((u >> 16) & 1u)) >> 16;
}
__device__ inline float bf2f(u16 u){
  return __uint_as_float(((u32)u) << 16);
}
__device__ inline float frcp(float x){
#if __has_builtin(__builtin_amdgcn_rcpf)
  return __builtin_amdgcn_rcpf(x);
#else
  return 1.f / x;
#endif
}

typedef _Float16 h2_t __attribute__((ext_vector_type(2)));
__device__ inline float dot2f(u32 w, u32 h, float acc){
#if __has_builtin(__builtin_amdgcn_fdot2)
  return __builtin_amdgcn_fdot2(__builtin_bit_cast(h2_t, w),
                                __builtin_bit_cast(h2_t, h), acc, false);
#else
  float r;
  asm("v_dot2_f32_f16 %0, %1, %2, %3" : "=v"(r) : "v"(w), "v"(h), "v"(acc));
  return r;
#endif
}
#define PIN4(v) asm volatile("" : "+v"((v).x), "+v"((v).y), "+v"((v).z), "+v"((v).w))

// ---------------- ws-size diagnostic sentinel ----------------
__global__ void k_sentinel(float* __restrict__ out, int n, float val){
  int i = blockIdx.x * 256 + threadIdx.x;
  if (i < n) out[i] = val;
}

// ---------------- CSR build ----------------
__global__ void k_zero(int* __restrict__ p){
  p[blockIdx.x * 256 + threadIdx.x] = 0;
}
__global__ void k_hist(const int* __restrict__ dst, int* __restrict__ deg){
  int e = blockIdx.x * 256 + threadIdx.x;
  atomicAdd(&deg[dst[e]], 1);
}
__global__ void k_s1(const int* __restrict__ deg, int* __restrict__ bsum){
  __shared__ int red[256];
  int t = threadIdx.x;
  red[t] = deg[blockIdx.x * 256 + t];
  __syncthreads();
  for (int s = 128; s; s >>= 1){ if (t < s) red[t] += red[t + s]; __syncthreads(); }
  if (!t) bsum[blockIdx.x] = red[0];
}
__global__ void k_s2(int* __restrict__ bsum){
  __shared__ int arr[512];
  int t = threadIdx.x;
  int v0 = (t < NCHUNK) ? bsum[t] : 0;
  arr[t] = v0; __syncthreads();
  for (int off = 1; off < 512; off <<= 1){
    int v = (t >= off) ? arr[t - off] : 0;
    __syncthreads();
    arr[t] += v;
    __syncthreads();
  }
  if (t < NCHUNK) bsum[t] = arr[t] - v0;   // exclusive
}
__global__ void k_s3(const int* __restrict__ bsum, int* __restrict__ row_ptr,
                     int* __restrict__ cursor){
  __shared__ int arr[256];
  int t = threadIdx.x;
  int i = blockIdx.x * 256 + t;
  int v0 = cursor[i];
  arr[t] = v0; __syncthreads();
  for (int off = 1; off < 256; off <<= 1){
    int v = (t >= off) ? arr[t - off] : 0;
    __syncthreads();
    arr[t] += v;
    __syncthreads();
  }
  int exc = arr[t] - v0 + bsum[blockIdx.x];
  row_ptr[i] = exc;
  cursor[i]  = exc;
  if (i == 0) row_ptr[NN] = EE;
}
__global__ void k_scatter(const int* __restrict__ src, const int* __restrict__ dst,
                          int* __restrict__ cursor, int* __restrict__ col){
  int e = blockIdx.x * 256 + threadIdx.x;
  int idx = atomicAdd(&cursor[dst[e]], 1);
  col[idx] = src[e];
}

// ---------------- centers: normalize + distance ----------------
__global__ void k_setup(const float* __restrict__ centers, float* __restrict__ cn,
                        float* __restrict__ dist_out){
  __shared__ float red[128];
  int t = threadIdx.x;
  for (int l = 0; l < 4; ++l){
    float v = centers[l*128 + t];
    red[t] = v * v; __syncthreads();
    for (int s = 64; s; s >>= 1){ if (t < s) red[t] += red[t + s]; __syncthreads(); }
    float nrm = sqrtf(red[0]);
    __syncthreads();
    cn[l*128 + t] = v / fmaxf(nrm, 1e-8f);
  }
  const int iu0[6] = {0,0,0,1,1,2}, iu1[6] = {1,2,3,2,3,3};
  __shared__ float dv[6];
  for (int p = 0; p < 6; ++p){
    float d = centers[iu0[p]*128 + t] - centers[iu1[p]*128 + t];
    red[t] = d * d; __syncthreads();
    for (int s = 64; s; s >>= 1){ if (t < s) red[t] += red[t + s]; __syncthreads(); }
    if (!t) dv[p] = sqrtf(red[0]);
    __syncthreads();
  }
  if (!t){
    float mean = 0.f;
    for (int p = 0; p < 6; ++p) mean += dv[p];
    mean /= 6.f;
    float var = 0.f;
    for (int p = 0; p < 6; ++p){ float d = dv[p] - mean; var += d * d; }
    var /= 5.f;                              // ddof=1
    dist_out[0] = -var;
  }
}

// ---------------- pos-enc tables + weight transforms ----------------
__global__ void k_pe(const float* __restrict__ projb, float* __restrict__ peb){
  int p = blockIdx.x, t = threadIdx.x;     // 1000 x 128
  float ex  = (float)(t >> 1) * (-2.0f * 9.210340371976184f / 128.0f);
  float ang = (float)p * expf(ex);
  float v = (t & 1) ? cosf(ang) : sinf(ang);
  peb[p*128 + t] = v + projb[t];
}
__global__ void k_pew(const float* __restrict__ peb, const float* __restrict__ Wih,
                      const float* __restrict__ bih, float* __restrict__ pew){
  int p = blockIdx.x;                       // 1000
  int j = blockIdx.y * 128 + threadIdx.x;   // 384
  const float* pb = peb + p*128;
  const float* wr = Wih + (size_t)j*128;
  float acc = bih[j];
  #pragma unroll 4
  for (int m = 0; m < 128; ++m) acc += pb[m] * wr[m];
  pew[(size_t)p*384 + j] = acc;
}
__global__ void k_combw(const float* __restrict__ projW, const float* __restrict__ Wih,
                        float* __restrict__ cw){
  int kk = blockIdx.x;                      // 128
  int j  = blockIdx.y * 128 + threadIdx.x;  // 384
  const float* pr = projW + (size_t)kk*128;
  const float* wr = Wih + (size_t)j*128;
  float acc = 0.f;
  #pragma unroll 4
  for (int m = 0; m < 128; ++m) acc += pr[m] * wr[m];
  cw[(size_t)kk*384 + j] = acc;
}
// Wk^T per layer
__global__ void k_tr(const float* __restrict__ Wk, float* __restrict__ wkt){
  int kk = blockIdx.x, l = blockIdx.y, c = threadIdx.x;
  wkt[(size_t)l*16384 + kk*128 + c] = Wk[(size_t)l*16384 + c*128 + kk];
}
// out[l][i] = row_i(M_l) . v_l
__global__ void k_mv(const float* __restrict__ M, const float* __restrict__ v,
                     float* __restrict__ out){
  int l = blockIdx.x, i = threadIdx.x;
  const float* row = M + (size_t)l*16384 + (size_t)i*128;
  const float* vv = v + l*128;
  float acc = 0.f;
  #pragma unroll 4
  for (int j = 0; j < 128; ++j) acc += row[j] * vv[j];
  out[l*128 + i] = acc;
}
// pack Whh rows as f16x2 along k
__global__ void k_packwhh16(const float* __restrict__ Whh, u32* __restrict__ wt){
  int kp = blockIdx.x;                      // 64
  int j  = blockIdx.y * 128 + threadIdx.x;  // 384
  _Float16 a = (_Float16)Whh[(size_t)j*128 + 2*kp];
  _Float16 b = (_Float16)Whh[(size_t)j*128 + 2*kp + 1];
  u32 lo = (u32)__builtin_bit_cast(u16, a);
  u32 hi = (u32)__builtin_bit_cast(u16, b);
  wt[(size_t)j*64 + kp] = (hi << 16) | lo;
}

// ---------------- GEMM v6: 128x128 tile, 8x8 acc; K=256 opt; LN opt; dstrow opt --
__global__ __launch_bounds__(256, 2) void k_gemm(
    const float* __restrict__ X, const float* __restrict__ W, int ldw,
    const float* __restrict__ X2, const float* __restrict__ W2,
    const float* __restrict__ bias, const float* __restrict__ pew,
    const int* __restrict__ pos, float* __restrict__ out,
    u16* __restrict__ outb, int ldo,
    const float* __restrict__ lng, const float* __restrict__ lnb,
    const float* __restrict__ bvv, const int* __restrict__ rowp,
    const int* __restrict__ dstrow){
  __shared__ __align__(16) float Wl[64*132];
  __shared__ __align__(16) float Xl[64*132];
  int tid = threadIdx.x;
  int rb = blockIdx.x * 128;
  int cb = blockIdx.y * 128;
  int rg = tid >> 4;
  int cg = tid & 15;
  int kxor = (cg >> 2) & 3;
  float acc[8][8];
  #pragma unroll
  for (int a = 0; a < 8; ++a)
    #pragma unroll
    for (int b = 0; b < 8; ++b) acc[a][b] = 0.f;
  int nhalf = X2 ? 4 : 2;
  for (int half = 0; half < nhalf; ++half){
    const float* Xs = (half < 2) ? X : X2;
    const float* Ws = (half < 2) ? W : W2;
    int ldws = (half < 2) ? ldw : 128;
    int hk = half & 1;
    __syncthreads();
    #pragma unroll
    for (int it = 0; it < 8; ++it){
      int idx = it*256 + tid;
      int kk = idx >> 5, c4 = idx & 31;
      *(float4*)&Wl[kk*132 + c4*4] =
          *(const float4*)&Ws[(size_t)(hk*64 + kk)*ldws + cb + c4*4];
    }
    #pragma unroll
    for (int it = 0; it < 8; ++it){
      int idx = it*256 + tid;
      int r = idx >> 4, c4 = idx & 15;
      float4 xv = *(const float4*)&Xs[(size_t)(rb + r)*128 + hk*64 + c4*4];
      Xl[(c4*4+0)*132 + r] = xv.x;
      Xl[(c4*4+1)*132 + r] = xv.y;
      Xl[(c4*4+2)*132 + r] = xv.z;
      Xl[(c4*4+3)*132 + r] = xv.w;
    }
    __syncthreads();
    #pragma unroll 2
    for (int kk = 0; kk < 64; ++kk){
      int kx = kk ^ kxor;
      float4 wa = *(const float4*)&Wl[kx*132 + cg*8];
      float4 wb = *(const float4*)&Wl[kx*132 + cg*8 + 4];
      float4 xa = *(const float4*)&Xl[kx*132 + rg*8];
      float4 xb = *(const float4*)&Xl[kx*132 + rg*8 + 4];
      float xs[8] = {xa.x, xa.y, xa.z, xa.w, xb.x, xb.y, xb.z, xb.w};
      float ws[8] = {wa.x, wa.y, wa.z, wa.w, wb.x, wb.y, wb.z, wb.w};
      #pragma unroll
      for (int rr = 0; rr < 8; ++rr)
        #pragma unroll
        for (int j = 0; j < 8; ++j) acc[rr][j] += xs[rr] * ws[j];
    }
  }
  if (lng){
    float gv[8], bl[8], bb[8], vv[8];
    #pragma unroll
    for (int j = 0; j < 8; ++j){
      int c = cg*8 + j;
      gv[j] = lng[c]; bl[j] = lnb[c]; bb[j] = bias[c]; vv[j] = bvv[c];
    }
    #pragma unroll
    for (int rr = 0; rr < 8; ++rr){
      int r = rb + rg*8 + rr;
      bool deg = rowp[r+1] > rowp[r];
      float rs = 0.f, rq = 0.f;
      #pragma unroll
      for (int j = 0; j < 8; ++j){
        float v = acc[rr][j] + bb[j] + (deg ? vv[j] : 0.f);
        acc[rr][j] = v;
        rs += v; rq += v*v;
      }
      #pragma unroll
      for (int o = 8; o; o >>= 1){ rs += __shfl_xor(rs, o); rq += __shfl_xor(rq, o); }
      float mu = rs * 0.0078125f;
      float var = rq * 0.0078125f - mu*mu;
      float rstd = rsqrtf(var + 1e-5f);
      float ov[8];
      #pragma unroll
      for (int j = 0; j < 8; ++j)
        ov[j] = fmaxf((acc[rr][j] - mu)*rstd*gv[j] + bl[j], 0.f);
      float* op = out + (size_t)r*128 + cg*8;
      *(float4*)op       = *(const float4*)&ov[0];
      *(float4*)(op + 4) = *(const float4*)&ov[4];
    }
    return;
  }
  #pragma unroll
  for (int rr = 0; rr < 8; ++rr){
    int r = rb + rg*8 + rr;
    float bv[8];
    if (pos){
      const float* pw = pew + (size_t)pos[r]*384 + cb + cg*8;
      #pragma unroll
      for (int j = 0; j < 8; ++j) bv[j] = pw[j];
    } else if (bias){
      #pragma unroll
      for (int j = 0; j < 8; ++j) bv[j] = bias[cb + cg*8 + j];
    } else {
      #pragma unroll
      for (int j = 0; j < 8; ++j) bv[j] = 0.f;
    }
    int orow = dstrow ? dstrow[r] : r;
    if (outb){
      u16 ob[8];
      #pragma unroll
      for (int j = 0; j < 8; ++j) ob[j] = (u16)bf16rne(acc[rr][j] + bv[j]);
      *(uint4*)(outb + (size_t)orow*ldo + cb + cg*8) = *(const uint4*)ob;
    } else {
      float ov[8];
      #pragma unroll
      for (int j = 0; j < 8; ++j) ov[j] = acc[rr][j] + bv[j];
      float* op = out + (size_t)orow*ldo + cb + cg*8;
      *(float4*)op       = *(const float4*)&ov[0];
      *(float4*)(op + 4) = *(const float4*)&ov[4];
    }
  }
}

// ---------------- fused edge v4: no qb, pair-unrolled ----------------
__global__ __launch_bounds__(256) void k_edge(
    const float* __restrict__ qt, const float* __restrict__ xsrc,
    const int* __restrict__ row_ptr, const int* __restrict__ col,
    float* __restrict__ xagg){
  int d = blockIdx.x * 8 + (threadIdx.x >> 5);
  int lane = threadIdx.x & 31;
  int e0 = row_ptr[d], e1 = row_ptr[d+1];
  if (e0 == e1){
    *(float4*)&xagg[(size_t)d*128 + lane*4] = make_float4(0.f, 0.f, 0.f, 0.f);
    return;
  }
  const float S = 0.08838834764831845f;   // 1/sqrt(128)
  float4 qv = *(const float4*)&qt[(size_t)d*128 + lane*4];
  float ss0 = 0.f, ss1 = 0.f;
  float4 A0 = make_float4(0.f,0.f,0.f,0.f), A1 = make_float4(0.f,0.f,0.f,0.f);
  int e = e0;
  for (; e + 1 < e1; e += 2){
    float4 x0 = *(const float4*)&xsrc[(size_t)col[e]  *128 + lane*4];
    float4 x1 = *(const float4*)&xsrc[(size_t)col[e+1]*128 + lane*4];
    float p0 = qv.x*x0.x + qv.y*x0.y + qv.z*x0.z + qv.w*x0.w;
    float p1 = qv.x*x1.x + qv.y*x1.y + qv.z*x1.z + qv.w*x1.w;
    #pragma unroll
    for (int o = 16; o; o >>= 1){ p0 += __shfl_xor(p0, o); p1 += __shfl_xor(p1, o); }
    float el0 = __expf(p0 * S);
    float el1 = __expf(p1 * S);
    ss0 += el0; ss1 += el1;
    A0.x += el0*x0.x; A0.y += el0*x0.y; A0.z += el0*x0.z; A0.w += el0*x0.w;
    A1.x += el1*x1.x; A1.y += el1*x1.y; A1.z += el1*x1.z; A1.w += el1*x1.w;
  }
  if (e < e1){
    float4 x0 = *(const float4*)&xsrc[(size_t)col[e]*128 + lane*4];
    float p0 = qv.x*x0.x + qv.y*x0.y + qv.z*x0.z + qv.w*x0.w;
    #pragma unroll
    for (int o = 16; o; o >>= 1) p0 += __shfl_xor(p0, o);
    float el0 = __expf(p0 * S);
    ss0 += el0;
    A0.x += el0*x0.x; A0.y += el0*x0.y; A0.z += el0*x0.z; A0.w += el0*x0.w;
  }
  float inv = 1.f / (ss0 + ss1);
  *(float4*)&xagg[(size_t)d*128 + lane*4] =
      make_float4((A0.x+A1.x)*inv, (A0.y+A1.y)*inv, (A0.z+A1.z)*inv, (A0.w+A1.w)*inv);
}

// ---------------- conv-3 lnrelu fused with cluster assignment ----------------
__global__ __launch_bounds__(256) void k_lnrelu_cls(
    const float* __restrict__ in, const float* __restrict__ g,
    const float* __restrict__ b, const float* __restrict__ bvv,
    const int* __restrict__ rowp, float* __restrict__ outp,
    const float* __restrict__ cn, const int* __restrict__ batch,
    const int* __restrict__ callsq, int* __restrict__ grp, int* __restrict__ inv){
  int node = blockIdx.x * 4 + (threadIdx.x >> 6);
  int lane = threadIdx.x & 63;
  float x0 = in[(size_t)node*128 + 2*lane], x1 = in[(size_t)node*128 + 2*lane + 1];
  if (rowp[node+1] > rowp[node]){
    x0 += bvv[2*lane];
    x1 += bvv[2*lane + 1];
  }
  float s = wredf(x0 + x1);
  float qq = wredf(x0*x0 + x1*x1);
  float mu = s * 0.0078125f;
  float var = qq * 0.0078125f - mu*mu;
  float rstd = rsqrtf(var + 1e-5f);
  float y0 = fmaxf((x0 - mu)*rstd*g[2*lane]   + b[2*lane],   0.f);
  float y1 = fmaxf((x1 - mu)*rstd*g[2*lane+1] + b[2*lane+1], 0.f);
  outp[(size_t)node*128 + 2*lane]     = y0;
  outp[(size_t)node*128 + 2*lane + 1] = y1;
  float p0 = y0*cn[      2*lane] + y1*cn[      2*lane+1];
  float p1 = y0*cn[128 + 2*lane] + y1*cn[128 + 2*lane+1];
  float p2 = y0*cn[256 + 2*lane] + y1*cn[256 + 2*lane+1];
  float p3 = y0*cn[384 + 2*lane] + y1*cn[384 + 2*lane+1];
  p0 = wredf(p0); p1 = wredf(p1); p2 = wredf(p2); p3 = wredf(p3);
  if (lane == 0){
    float best = p0; int bi = 0;
    if (p1 > best){ best = p1; bi = 1; }
    if (p2 > best){ best = p2; bi = 2; }
    if (p3 > best){ best = p3; bi = 3; }
    grp[node] = batch[node]*4 + bi;
    inv[callsq[node]] = node;
  }
}

// ---------------- grouping: chunked multisplit ----------------
__global__ __launch_bounds__(256) void k_g1(const int* __restrict__ inv,
                                            const int* __restrict__ grp,
                                            int* __restrict__ ch){
  __shared__ int hist[GG];
  int c = blockIdx.x, t = threadIdx.x;
  hist[t] = 0; hist[t + 256] = 0;
  __syncthreads();
  int g = grp[inv[c*256 + t]];
  atomicAdd(&hist[g], 1);
  __syncthreads();
  ch[c*GG + t] = hist[t];
  ch[c*GG + 256 + t] = hist[256 + t];
}
__global__ void k_g2(int* __restrict__ ch, int* __restrict__ cnt){
  __shared__ int arr[512];
  int g = blockIdx.x, t = threadIdx.x;
  int v0 = (t < NCHUNK) ? ch[(size_t)t*GG + g] : 0;
  arr[t] = v0; __syncthreads();
  for (int off = 1; off < 512; off <<= 1){
    int v = (t >= off) ? arr[t - off] : 0;
    __syncthreads();
    arr[t] += v;
    __syncthreads();
  }
  if (t < NCHUNK) ch[(size_t)t*GG + g] = arr[t] - v0;
  if (t == 511) cnt[g] = arr[511];
}
// scan group counts -> exclusive starts (packed gi layout)
__global__ void k_g4(const int* __restrict__ cnt, int* __restrict__ starts){
  __shared__ int arr[512];
  int t = threadIdx.x;
  int v0 = cnt[t];
  arr[t] = v0; __syncthreads();
  for (int off = 1; off < 512; off <<= 1){
    int v = (t >= off) ? arr[t - off] : 0;
    __syncthreads();
    arr[t] += v;
    __syncthreads();
  }
  starts[t] = arr[t] - v0;
}
__global__ __launch_bounds__(256) void k_g3(
    const int* __restrict__ inv, const int* __restrict__ grp,
    const int* __restrict__ ch, const int* __restrict__ starts,
    int* __restrict__ pos, int* __restrict__ dst, int* __restrict__ gn){
  __shared__ int hist[GG];
  int c = blockIdx.x, t = threadIdx.x;
  hist[t] = 0; hist[t + 256] = 0;
  __syncthreads();
  int node = inv[c*256 + t];
  int g = grp[node];
  int lane = t & 63, w = t >> 6;
  int before = 0, total = 0;
  for (int j = 0; j < 64; ++j){
    int gj = __shfl(g, j);
    if (gj == g){ total++; if (j < lane) before++; }
  }
  int base = 0;
  for (int wv = 0; wv < 4; ++wv){
    if (w == wv){
      base = hist[g];
      if (before == total - 1) hist[g] = base + total;
    }
    __syncthreads();
  }
  int p = ch[c*GG + g] + base + before;
  pos[node] = p;
  dst[node] = starts[g] + p;               // packed gi row
  gn[(size_t)g*SMAX + p] = node;
}

// ---------------- GRU v12: packed sequential gi rows + v9 structure --------------
// gi_pk row (starts[g]+p) is read sequentially per step; 2-deep raw-u16 lookahead.
// 256 threads; j = t>>1 owns output j, kh = t&1 owns k-half; lgkm-only barrier.
#define GRU_STEP(XR, XZ, XN, NODE, CUR, NXT)                                     \
  {                                                                              \
    const uint4* HB = (const uint4*)&hb16[CUR][0];                               \
    uint4 hh[8];                                                                 \
    _Pragma("unroll")                                                            \
    for (int s = 0; s < 8; ++s) hh[s] = HB[kh*8 + s];                            \
    __builtin_amdgcn_s_setprio(1);                                               \
    float ar = 0.f, az = 0.f, an = 0.f;                                          \
    _Pragma("unroll")                                                            \
    for (int s = 0; s < 8; ++s){                                                 \
      ar = dot2f(wr_[s].x, hh[s].x, ar); az = dot2f(wz_[s].x, hh[s].x, az); an = dot2f(wn_[s].x, hh[s].x, an); \
      ar = dot2f(wr_[s].y, hh[s].y, ar); az = dot2f(wz_[s].y, hh[s].y, az); an = dot2f(wn_[s].y, hh[s].y, an); \
      ar = dot2f(wr_[s].z, hh[s].z, ar); az = dot2f(wz_[s].z, hh[s].z, az); an = dot2f(wn_[s].z, hh[s].z, an); \
      ar = dot2f(wr_[s].w, hh[s].w, ar); az = dot2f(wz_[s].w, hh[s].w, az); an = dot2f(wn_[s].w, hh[s].w, an); \
    }                                                                            \
    ar += __shfl_xor(ar, 1); az += __shfl_xor(az, 1); an += __shfl_xor(an, 1);   \
    ar += br; az += bz; an += bn;                                                \
    float er = __expf(-((XR) + ar));                                             \
    float rg_ = frcp(1.f + er);                                                  \
    float ez = __expf(-((XZ) + az));                                             \
    float zg_ = frcp(1.f + ez);                                                  \
    float yv = (XN) + rg_ * an;                                                  \
    float e2 = __expf(-2.f * yv);                                                \
    float ng_ = (1.f - e2) * frcp(1.f + e2);                                     \
    float hnew = ng_ + zg_ * (hprev - ng_);                                      \
    __builtin_amdgcn_s_setprio(0);                                               \
    hprev = hnew;                                                                \
    if (!kh){                                                                    \
      _Float16 hf16 = (_Float16)hnew;                                            \
      hb16[NXT][j] = __builtin_bit_cast(u16, hf16);                              \
      node_out[(size_t)(NODE)*128 + j] = (u16)bf16rne(hnew);                     \
    }                                                                            \
    asm volatile("s_waitcnt lgkmcnt(0)" ::: "memory");                           \
    __builtin_amdgcn_s_barrier();                                                \
    asm volatile("" ::: "memory");                                               \
  }

__global__ __launch_bounds__(256)
__attribute__((amdgpu_waves_per_eu(2, 2)))
void k_gru(
    const u16* __restrict__ gi, const u32* __restrict__ wt,
    const float* __restrict__ bhh, const int* __restrict__ gn,
    const int* __restrict__ cnt, const int* __restrict__ starts,
    u16* __restrict__ node_out){
  __shared__ __align__(16) u16 hb16[2][128];
  int t = threadIdx.x;
  int j = t >> 1;
  int kh = t & 1;
  int g = blockIdx.x;
  int my = cnt[g];
  if (my <= 1) return;
  uint4 wr_[8], wz_[8], wn_[8];
  {
    const uint4* wt4 = (const uint4*)wt;
    size_t b0 = (size_t)(0*128 + j)*16 + kh*8;
    size_t b1 = (size_t)(1*128 + j)*16 + kh*8;
    size_t b2 = (size_t)(2*128 + j)*16 + kh*8;
    #pragma unroll
    for (int s = 0; s < 8; ++s){
      wr_[s] = wt4[b0 + s];
      wz_[s] = wt4[b1 + s];
      wn_[s] = wt4[b2 + s];
    }
    #pragma unroll
    for (int s = 0; s < 8; ++s){
      PIN4(wr_[s]); PIN4(wz_[s]); PIN4(wn_[s]);
    }
  }
  if (t < 128) hb16[0][t] = 0;
  float br = bhh[j], bz = bhh[128 + j], bn = bhh[256 + j];
  const int* gnr = gn + (size_t)g*SMAX;
  const u16* grow = gi + (size_t)starts[g]*384;   // packed rows, sequential
  float hprev = 0.f;
  // 2-deep raw lookahead: A = even steps, B = odd steps
  u16 a_r = grow[j], a_z = grow[128 + j], a_n = grow[256 + j];
  const u16* g1r = grow + (size_t)min(1, my - 1)*384;
  u16 b_r = g1r[j], b_z = g1r[128 + j], b_n = g1r[256 + j];
  int nodeA = gnr[0];
  int nodeB = gnr[min(1, my - 1)];
  __syncthreads();                       // init barrier (full drain once)
  for (int p = 0; p < my; p += 2){
    // even step p: consume A, reissue A for p+2
    float xr = bf2f(a_r), xz = bf2f(a_z), xn = bf2f(a_n);
    int nA = nodeA;
    {
      const u16* g2r = grow + (size_t)min(p + 2, my - 1)*384;
      a_r = g2r[j]; a_z = g2r[128 + j]; a_n = g2r[256 + j];
      nodeA = gnr[min(p + 2, my - 1)];
    }
    GRU_STEP(xr, xz, xn, nA, 0, 1);
    if (p + 1 >= my) break;
    // odd step p+1: consume B, reissue B for p+3
    float yr = bf2f(b_r), yz = bf2f(b_z), yn = bf2f(b_n);
    int nB = nodeB;
    {
      const u16* g3r = grow + (size_t)min(p + 3, my - 1)*384;
      b_r = g3r[j]; b_z = g3r[128 + j]; b_n = g3r[256 + j];
      nodeB = gnr[min(p + 3, my - 1)];
    }
    GRU_STEP(yr, yz, yn, nB, 1, 0);
  }
}

// ---------------- head fused with post-GRU LN+ReLU ----------------
__global__ __launch_bounds__(256) void k_head(
    const float* __restrict__ h, const u16* __restrict__ node_out,
    const int* __restrict__ grp, const int* __restrict__ cnt,
    const float* __restrict__ sqg, const float* __restrict__ sqb,
    const float* __restrict__ l1W, const float* __restrict__ l1b,
    const float* __restrict__ l2W, const float* __restrict__ l2b,
    float* __restrict__ out){
  int node = blockIdx.x * 4 + (threadIdx.x >> 6);
  int lane = threadIdx.x & 63;
  bool single = (cnt[grp[node]] == 1);   // wave-uniform
  float x0, x1;
  if (single){
    x0 = h[(size_t)node*128 + 2*lane];
    x1 = h[(size_t)node*128 + 2*lane + 1];
  } else {
    float r0 = bf2f(node_out[(size_t)node*128 + 2*lane]);
    float r1 = bf2f(node_out[(size_t)node*128 + 2*lane + 1]);
    float s = wredf(r0 + r1);
    float qq = wredf(r0*r0 + r1*r1);
    float mu = s * 0.0078125f;
    float var = qq * 0.0078125f - mu*mu;
    float rstd = rsqrtf(var + 1e-5f);
    x0 = fmaxf((r0 - mu)*rstd*sqg[2*lane]   + sqb[2*lane],   0.f);
    x1 = fmaxf((r1 - mu)*rstd*sqg[2*lane+1] + sqb[2*lane+1], 0.f);
  }
  float acc[8];
  #pragma unroll
  for (int j = 0; j < 8; ++j)
    acc[j] = x0 * l1W[(2*lane)*8 + j] + x1 * l1W[(2*lane + 1)*8 + j];
  #pragma unroll
  for (int o = 32; o; o >>= 1)
    #pragma unroll
    for (int j = 0; j < 8; ++j) acc[j] += __shfl_xor(acc[j], o);
  if (lane == 0){
    float zz = l2b[0];
    #pragma unroll
    for (int j = 0; j < 8; ++j){
      float xx = acc[j] + l1b[j];
      float ge = 0.5f * xx * (1.f + erff(xx * 0.7071067811865476f));
      zz += ge * l2W[j];
    }
    out[node] = 1.f / (1.f + expf(-zz));
  }
}

extern "C" void kernel_launch(void* const* d_in, const int* in_sizes, int n_in,
                              void* d_out, int out_size, void* d_ws, size_t ws_size,
                              hipStream_t stream){
  float* out = (float*)d_out;

  // ---- ws-size guard ----
  if (ws_size < WS_NEEDED){
    float code = -(float)(ws_size >> 20);
    k_sentinel<<<(out_size + 255)/256, 256, 0, stream>>>(out, out_size, code);
    return;
  }

  const float* x       = (const float*)d_in[0];
  const int*   tei     = (const int*)d_in[1];
  const int*   callsq  = (const int*)d_in[2];
  const int*   batch   = (const int*)d_in[3];
  const float* Wq      = (const float*)d_in[4];
  const float* bq      = (const float*)d_in[5];
  const float* Wk      = (const float*)d_in[6];
  const float* bk      = (const float*)d_in[7];
  const float* Wv      = (const float*)d_in[8];
  const float* bv      = (const float*)d_in[9];
  const float* Wsk     = (const float*)d_in[10];
  const float* bsk     = (const float*)d_in[11];
  const float* lng     = (const float*)d_in[12];
  const float* lnb     = (const float*)d_in[13];
  const float* centers = (const float*)d_in[14];
  const float* projW   = (const float*)d_in[15];
  const float* projb   = (const float*)d_in[16];
  const float* Wih     = (const float*)d_in[17];
  const float* Whh     = (const float*)d_in[18];
  const float* bih     = (const float*)d_in[19];
  const float* bhh     = (const float*)d_in[20];
  const float* sqg     = (const float*)d_in[21];
  const float* sqb     = (const float*)d_in[22];
  const float* l1W     = (const float*)d_in[23];
  const float* l1b     = (const float*)d_in[24];
  const float* l2W     = (const float*)d_in[25];
  const float* l2b     = (const float*)d_in[26];

  float* wf = (float*)d_ws;
  float* f_h    = wf + F_H;
  float* f_a    = wf + F_A;
  float* f_b    = wf + F_B;
  float* f_cn   = wf + F_CN;
  float* f_wkt  = wf + F_WKT;
  float* f_wqk  = wf + F_WQK;
  float* f_bqk  = wf + F_BQK;
  float* f_cw   = wf + F_CW;
  float* f_pew  = wf + F_PEW;
  float* f_peb  = wf + F_PEB;
  u16*   gi_bf  = (u16*)(wf + F_A);
  u16*   no_bf  = (u16*)(wf + F_NODE);
  int* wi = (int*)(wf + F_END);
  int* i_rowp = wi + I_ROWP;
  int* i_cur  = wi + I_CUR;
  int* i_col  = wi + I_COL;
  int* i_grp  = wi + I_GRP;
  int* i_inv  = wi + I_INV;
  int* i_pos  = wi + I_POS;
  int* i_gn   = wi + I_GN;
  int* i_cnt  = wi + I_CNT;
  int* i_ch   = wi + I_CH;
  int* i_bs   = wi + I_BS;
  u32* i_wt   = (u32*)(wi + I_WT);
  int* i_dst  = wi + I_DST;
  int* i_st   = wi + I_STARTS;

  const int* esrc = tei;
  const int* edst = tei + EE;

  // CSR build
  k_zero<<<NN/256, 256, 0, stream>>>(i_cur);
  k_hist<<<EE/256, 256, 0, stream>>>(edst, i_cur);
  k_s1<<<NCHUNK, 256, 0, stream>>>(i_cur, i_bs);
  k_s2<<<1, 512, 0, stream>>>(i_bs);
  k_s3<<<NCHUNK, 256, 0, stream>>>(i_bs, i_rowp, i_cur);
  k_scatter<<<EE/256, 256, 0, stream>>>(esrc, edst, i_cur, i_col);

  // centers, PE tables, folded conv weights, packed f16 Whh rows
  k_setup<<<1, 128, 0, stream>>>(centers, f_cn, out + NN);
  k_pe<<<1000, 128, 0, stream>>>(projb, f_peb);
  k_pew<<<dim3(1000, 3), 128, 0, stream>>>(f_peb, Wih, bih, f_pew);
  k_tr<<<dim3(128, 3), 128, 0, stream>>>(Wk, f_wkt);
  for (int i = 0; i < 3; ++i)
    k_gemm<<<dim3(1, 1), 256, 0, stream>>>(Wq + (size_t)i*16384, f_wkt + (size_t)i*16384,
        128, nullptr, nullptr, nullptr, nullptr, nullptr, f_wqk + (size_t)i*16384,
        nullptr, 128, nullptr, nullptr, nullptr, nullptr, nullptr); // Wqk = Wq@Wk^T
  k_mv<<<3, 128, 0, stream>>>(Wk, bq, f_bqk);                // bqk = Wk@bq
  k_combw<<<dim3(128, 3), 128, 0, stream>>>(projW, Wih, f_cw);
  k_packwhh16<<<dim3(64, 3), 128, 0, stream>>>(Whh, i_wt);

  // 3x TransformerConv + relu(LN)
  for (int i = 0; i < 3; ++i){
    const float* xin = i ? f_h : x;
    size_t wo = (size_t)i * 128 * 128, bo = (size_t)i * 128;
    // qt = xin@Wqk + bqk -> B
    k_gemm<<<dim3(NN/128, 1), 256, 0, stream>>>(xin, f_wqk + (size_t)i*16384, 128,
        nullptr, nullptr, f_bqk + bo, nullptr, nullptr, f_b, nullptr, 128,
        nullptr, nullptr, nullptr, nullptr, nullptr);
    // fused edge: xagg -> A
    k_edge<<<NN/8, 256, 0, stream>>>(f_b, xin, i_rowp, i_col, f_a);
    // h2 = xagg@Wv + xin@Wsk + bsk; convs 1-2 fuse LN+ReLU into epilogue -> f_h
    if (i < 2){
      k_gemm<<<dim3(NN/128, 1), 256, 0, stream>>>(f_a, Wv + wo, 128, xin, Wsk + wo,
          bsk + bo, nullptr, nullptr, f_h, nullptr, 128,
          lng + bo, lnb + bo, bv + bo, i_rowp, nullptr);
    } else {
      k_gemm<<<dim3(NN/128, 1), 256, 0, stream>>>(f_a, Wv + wo, 128, xin, Wsk + wo,
          bsk + bo, nullptr, nullptr, f_b, nullptr, 128,
          nullptr, nullptr, nullptr, nullptr, nullptr);
      k_lnrelu_cls<<<NN/4, 256, 0, stream>>>(f_b, lng + bo, lnb + bo, bv + bo, i_rowp,
          f_h, f_cn, batch, callsq, i_grp, i_inv);
    }
  }

  // grouping (+ packed-row scan)
  k_g1<<<NCHUNK, 256, 0, stream>>>(i_inv, i_grp, i_ch);
  k_g2<<<GG, 512, 0, stream>>>(i_ch, i_cnt);
  k_g4<<<1, 512, 0, stream>>>(i_cnt, i_st);
  k_g3<<<NCHUNK, 256, 0, stream>>>(i_inv, i_grp, i_ch, i_st, i_pos, i_dst, i_gn);

  // gi = h @ (projW@Wih^T) + PEW[pos] -> bf16, PACKED by visit order (dst rows)
  k_gemm<<<dim3(NN/128, 3), 256, 0, stream>>>(f_h, f_cw, 384, nullptr, nullptr,
      nullptr, f_pew, i_pos, nullptr, gi_bf, 384, nullptr, nullptr, nullptr, nullptr,
      i_dst);

  // GRU (sequential packed gi rows; raw h out); LN+ReLU deferred into head
  k_gru<<<GG, 256, 0, stream>>>(gi_bf, i_wt, bhh, i_gn, i_cnt, i_st, no_bf);

  // head (fused post-LN)
  k_head<<<NN/4, 256, 0, stream>>>(f_h, no_bf, i_grp, i_cnt, sqg, sqb,
                                   l1W, l1b, l2W, l2b, out);
}